// Round 9
// baseline (298.997 us; speedup 1.0000x reference)
//
#include <hip/hip_runtime.h>

typedef unsigned short u16;
typedef short bf16x8 __attribute__((ext_vector_type(8)));
typedef float f32x4 __attribute__((ext_vector_type(4)));

__device__ __forceinline__ float b2f(u16 u){ return __uint_as_float(((unsigned)u)<<16); }
__device__ __forceinline__ u16 f2bf(float f){ return (u16)((__float_as_uint(f)+0x8000u)>>16); }
__device__ __forceinline__ float ldf(const void* p, int i, bool isbf){
  return isbf ? b2f(((const u16*)p)[i]) : ((const float*)p)[i];
}
__device__ __forceinline__ float2 ld2(const void* p, int i, bool isbf){
  if (isbf) { unsigned u = *(const unsigned*)((const u16*)p + i);
              return make_float2(b2f((u16)(u & 0xffffu)), b2f((u16)(u >> 16))); }
  return *(const float2*)((const float*)p + i);
}
// prefetch-to-regs / store-to-LDS pair for the proj staging pipeline
__device__ __forceinline__ void pre8(uint4& A, uint4& B, const void* p, int i, bool isb){
  if (isb) { A = *(const uint4*)((const u16*)p + i); }
  else { A = *(const uint4*)((const float*)p + i);
         B = *(const uint4*)((const float*)p + i + 4); }
}
__device__ __forceinline__ void st8(u16* dst, const uint4& A, const uint4& B, bool isb){
  if (isb) { *(uint4*)dst = A; }
  else {
    const float* a = (const float*)&A; const float* b = (const float*)&B;
    dst[0]=f2bf(a[0]); dst[1]=f2bf(a[1]); dst[2]=f2bf(a[2]); dst[3]=f2bf(a[3]);
    dst[4]=f2bf(b[0]); dst[5]=f2bf(b[1]); dst[6]=f2bf(b[2]); dst[7]=f2bf(b[3]);
  }
}
__device__ __forceinline__ float c8(const float* __restrict__ p, int i, int stride){
  float s = 0.f;
  #pragma unroll
  for (int k = 0; k < 8; k++) s += p[i + k*stride];
  return s;
}
// LDS-only barrier: drains ds ops for cross-wave visibility but leaves global
// (prefetch) loads in flight.
__device__ __forceinline__ void bar(){ asm volatile("s_waitcnt lgkmcnt(0)\n\ts_barrier" ::: "memory"); }
// max across each 16-lane DPP row via rotations (VALU-speed, no LDS pipe)
#define RORMAX(x, ctrl) fmaxf((x), __int_as_float(__builtin_amdgcn_update_dpp( \
    __float_as_int(x), __float_as_int(x), (ctrl), 0xF, 0xF, false)))
#define MFMA16(a,b,c) __builtin_amdgcn_mfma_f32_16x16x32_bf16((a),(b),(c),0,0,0)

// ---------------------------------------------------------------------------
// Fused: cos/sin table (+flag) AND QKV split-K projection.
// Blocks 0..1007: ctab. Blocks 1008..1775: proj (96 n-blocks x 8 k-slices).
// Proj blocks recompute the dtype flag locally from `hidden` (deterministic,
// identical result) so there is no intra-kernel dependency on block 0.
// NOTE (R6 lesson): do NOT fuse stages that need cross-block completion —
// the __threadfence() completion-counter pattern cost +147us on attn
// (device-scope fence => L2 writeback per block, uniform 3.8x dilation).
// ---------------------------------------------------------------------------
__global__ __launch_bounds__(256) void ctab_proj_kernel(
    const u16* __restrict__ h, int* __restrict__ flag, float2* __restrict__ ctab,
    const void* __restrict__ Wa, const void* __restrict__ Wb, const void* __restrict__ Wc,
    float* __restrict__ out32)
{
  __shared__ __align__(16) u16 XW[2][64][136];     // proj tiles; ctab reuses as int[]
  int tid = threadIdx.x;

  if (blockIdx.x < 1008) {                         // ================= ctab part
    if (blockIdx.x == 0) {                         // dtype detect
      int c = 0;
      for (int i = tid; i < 4096; i += 256) {
        int e = (h[i] >> 7) & 0xFF;
        c += (e >= 116 && e <= 132) ? 1 : 0;
      }
      int* sh = (int*)XW;
      sh[tid] = c; __syncthreads();
      for (int s = 128; s > 0; s >>= 1) { if (tid < s) sh[tid] += sh[tid + s]; __syncthreads(); }
      if (tid == 0) flag[0] = (sh[0] >= 3100) ? 1 : 0;
    }
    int idx = blockIdx.x * 256 + tid;              // 258048 exact
    int dm = idx & 63, t = idx >> 6;
    float f = exp2f(-(float)dm * (13.287712379549449f / 64.0f));
    float ang = (float)t * f;
    float s, c;
    sincosf(ang, &s, &c);
    ctab[idx] = make_float2(c, s);
    return;
  }
  // ======================================================= proj part
  int bx = blockIdx.x - 1008;
  int n0 = (bx % 96) * 64;
  int ks0 = (bx / 96) * 512;
  // local dtype detection (same result in every block)
  int tot;
  {
    int c = 0;
    for (int i = tid; i < 4096; i += 256) {
      int e = (h[i] >> 7) & 0xFF;
      c += (e >= 116 && e <= 132) ? 1 : 0;
    }
    int* sh = (int*)XW;
    sh[tid] = c; __syncthreads();
    for (int s = 128; s > 0; s >>= 1) { if (tid < s) sh[tid] += sh[tid + s]; __syncthreads(); }
    tot = sh[0];
    __syncthreads();                               // sh dead before tile staging
  }
  bool fbf = (tot >= 3100);
  bool xbf = fbf;                                  // x = hidden (dynamic dtype)
  const void* X = h;
  const void* W; int wr0;
  if (n0 < 4096)      { W = Wa; wr0 = n0; }
  else if (n0 < 5120) { W = Wb; wr0 = n0 - 4096; }
  else                { W = Wc; wr0 = n0 - 5120; }

  int wv = tid >> 6, lane = tid & 63, lr = lane & 15, lq = lane >> 4;
  f32x4 zf = {0.f,0.f,0.f,0.f};
  f32x4 acc[4] = {zf, zf, zf, zf};

  uint4 xa[4], xb[4], wa[4], wb[4];                // one prefetch generation
  #pragma unroll
  for (int s = 0; s < 4; s++) {
    int e = s * 256 + tid, row = e >> 4, c8i = e & 15;
    pre8(xa[s], xb[s], X, row * 4096 + ks0 + c8i * 8, xbf);
    pre8(wa[s], wb[s], W, (wr0 + row) * 4096 + ks0 + c8i * 8, fbf);
  }
  #pragma unroll 1
  for (int ki = 0; ki < 4; ki++) {
    bar();                                         // prev MFMA reads done
    #pragma unroll
    for (int s = 0; s < 4; s++) {
      int e = s * 256 + tid, row = e >> 4, c8i = e & 15;
      st8(&XW[0][row][c8i * 8], xa[s], xb[s], xbf);
      st8(&XW[1][row][c8i * 8], wa[s], wb[s], fbf);
    }
    if (ki < 3) {                                  // prefetch next k-slice
      int k0 = ks0 + (ki + 1) * 128;
      #pragma unroll
      for (int s = 0; s < 4; s++) {
        int e = s * 256 + tid, row = e >> 4, c8i = e & 15;
        pre8(xa[s], xb[s], X, row * 4096 + k0 + c8i * 8, xbf);
        pre8(wa[s], wb[s], W, (wr0 + row) * 4096 + k0 + c8i * 8, fbf);
      }
    }
    bar();                                         // LDS tiles visible
    #pragma unroll
    for (int ks = 0; ks < 4; ks++) {
      bf16x8 af = *(const bf16x8*)&XW[0][wv * 16 + lr][ks * 32 + lq * 8];
      #pragma unroll
      for (int nt = 0; nt < 4; nt++) {
        bf16x8 bv = *(const bf16x8*)&XW[1][nt * 16 + lr][ks * 32 + lq * 8];
        acc[nt] = MFMA16(af, bv, acc[nt]);
      }
    }
  }
  float* outp = out32 + (size_t)(bx / 96) * 64 * 6144;
  #pragma unroll
  for (int nt = 0; nt < 4; nt++)
    #pragma unroll
    for (int r = 0; r < 4; r++)
      outp[(wv * 16 + lq * 4 + r) * 6144 + n0 + nt * 16 + lr] = acc[nt][r];
}

// ---------------------------------------------------------------------------
// Split-K projection (standalone, used for Wo): partial = X[64][512] . W^T
// ---------------------------------------------------------------------------
__global__ __launch_bounds__(256) void proj_kernel(
    const void* __restrict__ X, const void* __restrict__ Wa,
    const void* __restrict__ Wb, const void* __restrict__ Wc,
    float* __restrict__ out32, int Na, int Nb, int ostride,
    const int* __restrict__ flagp, int x_dyn)
{
  bool fbf = (*flagp != 0);
  bool xbf = x_dyn ? fbf : true;
  int n0 = blockIdx.x * 64;
  int ks0 = blockIdx.y * 512;
  const void* W; int wr0;
  if (n0 < Na)           { W = Wa; wr0 = n0; }
  else if (n0 < Na + Nb) { W = Wb; wr0 = n0 - Na; }
  else                   { W = Wc; wr0 = n0 - Na - Nb; }

  __shared__ u16 Xs[64][136];
  __shared__ u16 Ws[64][136];
  int tid = threadIdx.x;
  int wv = tid >> 6, lane = tid & 63, lr = lane & 15, lq = lane >> 4;
  f32x4 zf = {0.f,0.f,0.f,0.f};
  f32x4 acc[4] = {zf, zf, zf, zf};

  uint4 xa[4], xb[4], wa[4], wb[4];
  #pragma unroll
  for (int s = 0; s < 4; s++) {
    int e = s * 256 + tid, row = e >> 4, c8i = e & 15;
    pre8(xa[s], xb[s], X, row * 4096 + ks0 + c8i * 8, xbf);
    pre8(wa[s], wb[s], W, (wr0 + row) * 4096 + ks0 + c8i * 8, fbf);
  }
  #pragma unroll 1
  for (int ki = 0; ki < 4; ki++) {
    bar();
    #pragma unroll
    for (int s = 0; s < 4; s++) {
      int e = s * 256 + tid, row = e >> 4, c8i = e & 15;
      st8(&Xs[row][c8i * 8], xa[s], xb[s], xbf);
      st8(&Ws[row][c8i * 8], wa[s], wb[s], fbf);
    }
    if (ki < 3) {
      int k0 = ks0 + (ki + 1) * 128;
      #pragma unroll
      for (int s = 0; s < 4; s++) {
        int e = s * 256 + tid, row = e >> 4, c8i = e & 15;
        pre8(xa[s], xb[s], X, row * 4096 + k0 + c8i * 8, xbf);
        pre8(wa[s], wb[s], W, (wr0 + row) * 4096 + k0 + c8i * 8, fbf);
      }
    }
    bar();
    #pragma unroll
    for (int ks = 0; ks < 4; ks++) {
      bf16x8 af = *(const bf16x8*)&Xs[wv * 16 + lr][ks * 32 + lq * 8];
      #pragma unroll
      for (int nt = 0; nt < 4; nt++) {
        bf16x8 bv = *(const bf16x8*)&Ws[nt * 16 + lr][ks * 32 + lq * 8];
        acc[nt] = MFMA16(af, bv, acc[nt]);
      }
    }
  }
  float* outp = out32 + (size_t)blockIdx.y * 64 * ostride;
  #pragma unroll
  for (int nt = 0; nt < 4; nt++)
    #pragma unroll
    for (int r = 0; r < 4; r++)
      outp[(wv * 16 + lq * 4 + r) * ostride + n0 + nt * 16 + lr] = acc[nt][r];
}

// ---------------------------------------------------------------------------
// Prep: RoPE'd Q [bh][32][128], RoPE'd full-K [bh][64][128], V_full^T [bh][128][64]
// R8: vfullT branch rebuilt as 64 one-bh LDS-transpose blocks (3072..3135).
// Old mapping read vfp/Cq32 with lanes varying t -> 512B/24.6KB stride scalar
// loads. Now phase A reads [t][d] lanes-vary-d (coalesced), T[64][130] pad
// makes phase-B reads 2-way-bank (free), phase B writes [d][t] contiguous.
// ---------------------------------------------------------------------------
__global__ __launch_bounds__(256) void prep_kernel(
    const float* __restrict__ Cq32, const void* __restrict__ kfp, const void* __restrict__ vfp,
    const float2* __restrict__ ctab, const int* __restrict__ flagp,
    u16* __restrict__ qrb, u16* __restrict__ kfullb, u16* __restrict__ vfullT)
{
  __shared__ u16 T[64][130];
  bool isbf = (*flagp != 0);
  int tid = threadIdx.x;
  if (blockIdx.x < 3072) {
    int idx = blockIdx.x * 256 + tid;
    if (idx < 262144) {                            // qr
      int d = idx & 127, row = (idx >> 7) & 31, bh = idx >> 12;
      int b = bh >> 3, kvh = bh & 7, g = row >> 3, qp = row & 7;
      int tok = b * 8 + qp, h = kvh * 4 + g;
      float x  = c8(Cq32, tok * 6144 + h * 128 + d, 393216);
      float x2 = c8(Cq32, tok * 6144 + h * 128 + (d ^ 64), 393216);
      float2 cs = ctab[(4024 + qp) * 64 + (d & 63)];
      float sgn = (d < 64) ? -1.f : 1.f;
      qrb[idx] = f2bf(x * cs.x + sgn * (x2 * cs.y));
    } else {                                       // k_full roped, pos = 3968+t
      int j = idx - 262144;
      int d = j & 127, t = (j >> 7) & 63, bh = j >> 13;
      int b = bh >> 3, kvh = bh & 7;
      float x, x2;
      if (t < 56) {
        x  = ldf(kfp, (bh * 56 + t) * 128 + d, isbf);
        x2 = ldf(kfp, (bh * 56 + t) * 128 + (d ^ 64), isbf);
      } else {
        int tok = b * 8 + (t - 56);
        x  = c8(Cq32, tok * 6144 + 4096 + kvh * 128 + d, 393216);
        x2 = c8(Cq32, tok * 6144 + 4096 + kvh * 128 + (d ^ 64), 393216);
      }
      float2 cs = ctab[(3968 + t) * 64 + (d & 63)];
      float sgn = (d < 64) ? -1.f : 1.f;
      kfullb[j] = f2bf(x * cs.x + sgn * (x2 * cs.y));
    }
  } else {                                         // v_full^T, one bh per block
    int bh = blockIdx.x - 3072;
    int b = bh >> 3, kvh = bh & 7;
    for (int u = tid; u < 8192; u += 256) {        // phase A: [t][d] coalesced
      int t = u >> 7, d = u & 127;
      float x;
      if (t < 56) x = ldf(vfp, (bh * 56 + t) * 128 + d, isbf);
      else        x = c8(Cq32, (b * 8 + t - 56) * 6144 + 5120 + kvh * 128 + d, 393216);
      T[t][d] = f2bf(x);
    }
    __syncthreads();
    for (int u = tid; u < 8192; u += 256) {        // phase B: [d][t] contiguous
      int d = u >> 6, t = u & 63;
      vfullT[bh * 8192 + u] = T[t][d];
    }
  }
}

// ---------------------------------------------------------------------------
// Online-flash attention, 64-key chunks, 4 per block, 2-phase software pipeline.
// Grid (64 bh, 16 grp). Chunks 0..61 quantized; 62 full; 63 skipped.
//   P1: S(c)=QK MFMA + DPP row-max + pmax write  ||  PV(c-1) MFMA + ones-MFMA
//   P2: alpha/exp + Pl(c) write + V-stage(c) + K-stage(c+1) + reg prefetch
// R8: KDEQ's 16 ctab float2 loads (exposed L2 round-trip inside P2) replaced
// by an angle-addition recurrence: cs(ii+1) = cs(ii) * csd (4 FMA), csd =
// ctab[64+lane] loaded once; the two ii=0 seeds prefetched in KLOAD. KDEQ is
// now pure VALU+ds_write. <=7 fp32 rotation steps from a table-exact seed:
// error ~1e-6, far below bf16 rounding.
// NOTE: plain __launch_bounds__(256). (256,4) capped VGPR at 64 and spilled
// ~140MB to scratch (R2). Keep the allocator free.
// NOTE: no fused combine — R6's completion-counter + __threadfence cost +147us.
// ---------------------------------------------------------------------------
__global__ __launch_bounds__(256) void attn_kernel(
    const int* __restrict__ kqw, const void* __restrict__ ksc, const void* __restrict__ kmn,
    const int* __restrict__ vqw, const void* __restrict__ vsc, const void* __restrict__ vmn,
    const u16* __restrict__ qrb, const u16* __restrict__ kfullb, const u16* __restrict__ vfullT,
    const float2* __restrict__ ctab, const int* __restrict__ flagp,
    u16* __restrict__ Opart, float* __restrict__ ml)
{
  bool isbf = (*flagp != 0);
  int bh = blockIdx.x, grp = blockIdx.y;
  int tid = threadIdx.x;
  int c0 = grp * 4;
  int N = (grp == 15) ? 3 : 4;                     // grp 15: chunks 60,61,62(full)

  __shared__ __align__(16) unsigned char L[37120];
  u16* Kt = (u16*)L;                               // [64 t][128 d] swz  16384 B
  u16* Vt = (u16*)(L + 16384);                     // [128 d][64 t] swz  16384 B
  u16* Pt = (u16*)(L + 32768);                     // [32 q][64 k] swz    4096 B
  float* pmax = (float*)(L + 36864);               // [4][16]

  int wv = tid >> 6, lane = tid & 63, lr = lane & 15, lq = lane >> 4;
  int mt = wv & 1, nh = wv >> 1;
  int sx = (lr & 7) << 3;                          // read-side XOR (row&7 == lr&7)

  const int* kq_lo = kqw + (bh * 128 + lane) * 496;
  const int* kq_hi = kq_lo + 64 * 496;
  int klo = (bh * 128 + lane) * 124;
  int khi = klo + 64 * 124;
  const int* vqp = vqw + (bh * 3968 + lane) * 16 + wv * 4;
  int voff = (bh * 3968 + lane) * 4 + wv;

  bf16x8 qa[4];
  #pragma unroll
  for (int ks = 0; ks < 4; ks++)
    qa[ks] = *(const bf16x8*)&qrb[(bh * 32 + mt * 16 + lr) * 128 + ks * 32 + lq * 8];
  bf16x8 onev;
  #pragma unroll
  for (int j2 = 0; j2 < 8; j2++) onev[j2] = (short)0x3F80;   // bf16 1.0
  float2 csd = ctab[64 + lane];                    // per-lane unit-step rotor

  float m_prev[4], l_run[4], alpha[4], mx[4];
  f32x4 zf = {0.f,0.f,0.f,0.f};
  f32x4 oacc[4] = {zf, zf, zf, zf};
  f32x4 sacc[2];
  #pragma unroll
  for (int r = 0; r < 4; r++) { m_prev[r] = -INFINITY; l_run[r] = 0.f; }

  // prefetch registers
  unsigned kwl[2], kwh[2];
  float2 ksl, kml, ksh, kmh;
  float2 ct0[2];
  uint4 vw; float vs, vm;

#define KLOAD(cn) do { \
    kwl[0] = kq_lo[(cn)*8 + wv]; kwl[1] = kq_lo[(cn)*8 + wv + 4]; \
    kwh[0] = kq_hi[(cn)*8 + wv]; kwh[1] = kq_hi[(cn)*8 + wv + 4]; \
    ksl = ld2(ksc, klo + (cn)*2, isbf); kml = ld2(kmn, klo + (cn)*2, isbf); \
    ksh = ld2(ksc, khi + (cn)*2, isbf); kmh = ld2(kmn, khi + (cn)*2, isbf); \
    ct0[0] = ctab[((cn)*64 + wv*8)*64 + lane]; \
    ct0[1] = ctab[((cn)*64 + (wv+4)*8)*64 + lane]; } while(0)
#define VLOAD(cn) do { \
    vw = *(const uint4*)(vqp + (cn)*1024); \
    vs = ldf(vsc, voff + (cn)*256, isbf); vm = ldf(vmn, voff + (cn)*256, isbf); } while(0)
#define KDEQ(cn) do { \
    _Pragma("unroll") \
    for (int it = 0; it < 2; it++) { \
      int w = wv + 4 * it; \
      unsigned w1 = kwl[it], w2 = kwh[it]; \
      float sc1 = it ? ksl.y : ksl.x, m1 = it ? kml.y : kml.x; \
      float sc2 = it ? ksh.y : ksh.x, m2 = it ? kmh.y : kmh.x; \
      float2 cs = ct0[it]; \
      _Pragma("unroll") \
      for (int ii = 0; ii < 8; ii++) { \
        float v1 = (float)((w1 >> (4 * ii)) & 15u) * sc1 + m1; \
        float v2 = (float)((w2 >> (4 * ii)) & 15u) * sc2 + m2; \
        int t = w * 8 + ii; \
        Kt[(t * 128 + lane)      ^ ((t & 7) << 3)] = f2bf(v1 * cs.x - v2 * cs.y); \
        Kt[(t * 128 + lane + 64) ^ ((t & 7) << 3)] = f2bf(v2 * cs.x + v1 * cs.y); \
        float nx = cs.x * csd.x - cs.y * csd.y; \
        cs.y = cs.y * csd.x + cs.x * csd.y; \
        cs.x = nx; \
      } \
    } } while(0)
#define PVSTEP() do { \
    f32x4 pv[4] = {zf, zf, zf, zf}; f32x4 ls = zf; \
    _Pragma("unroll") \
    for (int ks = 0; ks < 2; ks++) { \
      bf16x8 af = *(const bf16x8*)&Pt[((mt*16 + lr)*64 + ks*32 + lq*8) ^ sx]; \
      ls = MFMA16(af, onev, ls); \
      _Pragma("unroll") \
      for (int nt = 0; nt < 4; nt++) { \
        bf16x8 bv = *(const bf16x8*)&Vt[((nh*64 + nt*16 + lr)*64 + ks*32 + lq*8) ^ sx]; \
        pv[nt] = MFMA16(af, bv, pv[nt]); \
      } \
    } \
    _Pragma("unroll") \
    for (int r = 0; r < 4; r++) { \
      l_run[r] = l_run[r] * alpha[r] + ls[r]; \
      _Pragma("unroll") \
      for (int nt = 0; nt < 4; nt++) \
        oacc[nt][r] = oacc[nt][r] * alpha[r] + pv[nt][r]; \
    } } while(0)

  // ---- prologue: K(c0) -> Kt; refill K regs with c0+1 (always quant) ----
  KLOAD(c0);
  VLOAD(c0);
  KDEQ(c0);
  KLOAD(c0 + 1);
  bar();

  for (int i = 0; i < N; i++) {
    int c = c0 + i;
    // ================= P1: S(c) + PV(c-1) =================
    f32x4 sa0 = zf, sa1 = zf;
    #pragma unroll
    for (int ks = 0; ks < 4; ks++) {
      bf16x8 b0 = *(const bf16x8*)&Kt[((nh*32 + lr)*128      + ks*32 + lq*8) ^ sx];
      bf16x8 b1 = *(const bf16x8*)&Kt[((nh*32 + 16 + lr)*128 + ks*32 + lq*8) ^ sx];
      sa0 = MFMA16(qa[ks], b0, sa0);
      sa1 = MFMA16(qa[ks], b1, sa1);
    }
    if (i > 0) PVSTEP();                           // uses alpha from P2(i-1)
    #pragma unroll
    for (int r = 0; r < 4; r++) {
      sa0[r] *= 0.08838834764831845f;
      sa1[r] *= 0.08838834764831845f;
      float m0 = fmaxf(sa0[r], sa1[r]);
      m0 = RORMAX(m0, 0x128);                      // row_ror:8
      m0 = RORMAX(m0, 0x124);                      // row_ror:4
      m0 = RORMAX(m0, 0x122);                      // row_ror:2
      m0 = RORMAX(m0, 0x121);                      // row_ror:1
      mx[r] = m0;
    }
    if (lr == 0) {
      #pragma unroll
      for (int r = 0; r < 4; r++) pmax[wv * 16 + lq * 4 + r] = mx[r];
    }
    sacc[0] = sa0; sacc[1] = sa1;
    bar();
    // ================= P2: softmax + stage tiles ==========
    #pragma unroll
    for (int r = 0; r < 4; r++) {
      float cm = fmaxf(mx[r], pmax[(wv ^ 2) * 16 + lq * 4 + r]);
      float mn2 = fmaxf(m_prev[r], cm);
      alpha[r] = __expf(m_prev[r] - mn2);          // 0 on first chunk
      m_prev[r] = mn2;
    }
    #pragma unroll
    for (int nt = 0; nt < 2; nt++) {
      #pragma unroll
      for (int r = 0; r < 4; r++) {
        float p = __expf(sacc[nt][r] - m_prev[r]);
        int q = mt * 16 + lq * 4 + r, k = nh * 32 + nt * 16 + lr;
        Pt[(q * 64 + k) ^ ((q & 7) << 3)] = f2bf(p);
      }
    }
    // V-stage(c)
    if (c != 62) {
      unsigned wds[4] = {vw.x, vw.y, vw.z, vw.w};
      #pragma unroll
      for (int it = 0; it < 4; it++) {
        unsigned wd = wds[it];
        #pragma unroll
        for (int ii = 0; ii < 8; ii++) {
          int d = (wv * 4 + it) * 8 + ii;
          Vt[(d * 64 + lane) ^ ((d & 7) << 3)] = f2bf((float)((wd >> (4 * ii)) & 15u) * vs + vm);
        }
      }
    } else {
      for (int u = tid; u < 1024; u += 256) {
        int dd = u >> 3, t8 = u & 7;
        *(uint4*)&Vt[(dd * 64 + t8 * 8) ^ ((dd & 7) << 3)] =
            *(const uint4*)&vfullT[(bh * 128 + dd) * 64 + t8 * 8];
      }
    }
    // K-stage(c+1)
    if (i + 1 < N) {
      if (c + 1 == 62) {
        for (int u = tid; u < 1024; u += 256) {
          int row = u >> 4, cc = u & 15;
          *(uint4*)&Kt[(row * 128 + cc * 8) ^ ((row & 7) << 3)] =
              *(const uint4*)&kfullb[(bh * 64 + row) * 128 + cc * 8];
        }
      } else {
        KDEQ(c + 1);
      }
    }
    // register prefetch for the NEXT P2 (flight spans P1(i+1))
    if (i + 2 < N && c + 2 < 62) KLOAD(c + 2);
    if (i + 1 < N && c + 1 < 62) VLOAD(c + 1);
    bar();
  }
  // ---- epilogue: PV of last chunk ----
  PVSTEP();

  u16* Ob = Opart + (size_t)((bh * 16 + grp) * 32) * 128;
  #pragma unroll
  for (int nt = 0; nt < 4; nt++)
    #pragma unroll
    for (int r = 0; r < 4; r++)
      Ob[(mt * 16 + lq * 4 + r) * 128 + nh * 64 + nt * 16 + lr] = f2bf(oacc[nt][r]);
  if (wv < 2 && lr == 0) {
    #pragma unroll
    for (int r = 0; r < 4; r++) {
      ml[((bh * 16 + grp) * 32 + mt * 16 + lq * 4 + r) * 2 + 0] = m_prev[r];
      ml[((bh * 16 + grp) * 32 + mt * 16 + lq * 4 + r) * 2 + 1] = l_run[r];
    }
  }
#undef KLOAD
#undef VLOAD
#undef KDEQ
#undef PVSTEP
}

// ---------------------------------------------------------------------------
// Combine 16 group partials per bh. Grid (64, 4 d-quarters).
// ---------------------------------------------------------------------------
__global__ __launch_bounds__(256) void combine_kernel(
    const u16* __restrict__ Opart, const float* __restrict__ ml, u16* __restrict__ attn_out)
{
  int bh = blockIdx.x, dq = blockIdx.y, tid = threadIdx.x;
  __shared__ float Wg[16][33];
  __shared__ float Ls[32];
  if (tid < 32) {
    int row = tid;
    float M = -INFINITY;
    for (int g = 0; g < 16; g++)
      M = fmaxf(M, ml[((bh * 16 + g) * 32 + row) * 2]);
    float Lacc = 0.f;
    for (int g = 0; g < 16; g++) {
      float m = ml[((bh * 16 + g) * 32 + row) * 2];
      float l = ml[((bh * 16 + g) * 32 + row) * 2 + 1];
      float w = __expf(m - M);
      Wg[g][row] = w;
      Lacc += l * w;
    }
    Ls[row] = Lacc;
  }
  __syncthreads();
  int row = tid >> 3, ds = tid & 7;
  int d0 = dq * 32 + ds * 4;
  float a0 = 0.f, a1 = 0.f, a2 = 0.f, a3 = 0.f;
  for (int g = 0; g < 16; g++) {
    float w = Wg[g][row];
    const u16* p = Opart + (size_t)((bh * 16 + g) * 32 + row) * 128 + d0;
    uint2 v = *(const uint2*)p;
    const u16* h = (const u16*)&v;
    a0 += w * b2f(h[0]); a1 += w * b2f(h[1]); a2 += w * b2f(h[2]); a3 += w * b2f(h[3]);
  }
  float inv = 1.0f / Ls[row];
  int b = bh >> 3, kvh = bh & 7, hg = row >> 3, qp = row & 7;
  u16* dst = attn_out + (size_t)(b * 8 + qp) * 4096 + (kvh * 4 + hg) * 128 + d0;
  dst[0] = f2bf(a0 * inv); dst[1] = f2bf(a1 * inv);
  dst[2] = f2bf(a2 * inv); dst[3] = f2bf(a3 * inv);
}

// ---------------------------------------------------------------------------
// Sum 8 Wo K-split partials, emit final output in detected dtype.
// ---------------------------------------------------------------------------
__global__ __launch_bounds__(256) void cast_kernel(
    const float* __restrict__ O32, const int* __restrict__ flagp, void* __restrict__ out)
{
  int i = blockIdx.x * 256 + threadIdx.x;          // 262144 exact
  float v = c8(O32, i, 262144);
  if (*flagp) ((u16*)out)[i] = f2bf(v);
  else        ((float*)out)[i] = v;
}

// ---------------------------------------------------------------------------
extern "C" void kernel_launch(void* const* d_in, const int* in_sizes, int n_in,
                              void* d_out, int out_size, void* d_ws, size_t ws_size,
                              hipStream_t stream)
{
  const void* hidden = d_in[0];
  const void* Wq  = d_in[1];
  const void* Wk  = d_in[2];
  const void* Wv  = d_in[3];
  const void* Wo  = d_in[4];
  const int*  kqw = (const int*)d_in[5];
  const void* ksc = d_in[6];
  const void* kmn = d_in[7];
  const void* kfp = d_in[8];
  const int*  vqw = (const int*)d_in[9];
  const void* vsc = d_in[10];
  const void* vmn = d_in[11];
  const void* vfp = d_in[12];

  char* ws = (char*)d_ws;
  int*    flag     = (int*)(ws);                    //        256
  float2* ctab     = (float2*)(ws + 256);           //  2,064,384
  float*  Cq32     = (float*)(ws + 2064640);        // regionA 16,777,216:
  u16*    Opart    = (u16*)(ws + 2064640);          //   Cq32 12.6MB / Opart 8.4MB / O32 8.4MB
  float*  O32      = (float*)(ws + 2064640);        //   (pairwise-disjoint lifetimes)
  u16*    qrb      = (u16*)(ws + 18841856);         //    524,288 (attn_out overlays)
  u16*    attn_out = qrb;
  u16*    kfullb   = (u16*)(ws + 19366144);         //  1,048,576
  u16*    vfullT   = (u16*)(ws + 20414720);         //  1,048,576
  float*  ml       = (float*)(ws + 21463296);       //    524,288 (uses 262,144)

  ctab_proj_kernel<<<1776, 256, 0, stream>>>((const u16*)hidden, flag, ctab,
                                             Wq, Wk, Wv, Cq32);
  prep_kernel<<<3136, 256, 0, stream>>>(Cq32, kfp, vfp, ctab, flag, qrb, kfullb, vfullT);
  attn_kernel<<<dim3(64, 16), 256, 0, stream>>>(kqw, ksc, kmn, vqw, vsc, vmn,
                                                qrb, kfullb, vfullT, ctab, flag, Opart, ml);
  combine_kernel<<<dim3(64, 4), 256, 0, stream>>>(Opart, ml, attn_out);
  proj_kernel<<<dim3(64, 8), 256, 0, stream>>>(attn_out, Wo, Wo, Wo, O32, 4096, 0, 4096, flag, 0);
  cast_kernel<<<1024, 256, 0, stream>>>(O32, flag, d_out);
}

// Round 10
// 295.276 us; speedup vs baseline: 1.0126x; 1.0126x over previous
//
#include <hip/hip_runtime.h>

typedef unsigned short u16;
typedef short bf16x8 __attribute__((ext_vector_type(8)));
typedef float f32x4 __attribute__((ext_vector_type(4)));

__device__ __forceinline__ float b2f(u16 u){ return __uint_as_float(((unsigned)u)<<16); }
__device__ __forceinline__ u16 f2bf(float f){ return (u16)((__float_as_uint(f)+0x8000u)>>16); }
__device__ __forceinline__ float ldf(const void* p, int i, bool isbf){
  return isbf ? b2f(((const u16*)p)[i]) : ((const float*)p)[i];
}
__device__ __forceinline__ float2 ld2(const void* p, int i, bool isbf){
  if (isbf) { unsigned u = *(const unsigned*)((const u16*)p + i);
              return make_float2(b2f((u16)(u & 0xffffu)), b2f((u16)(u >> 16))); }
  return *(const float2*)((const float*)p + i);
}
// prefetch-to-regs / store-to-LDS pair for the proj staging pipeline
__device__ __forceinline__ void pre8(uint4& A, uint4& B, const void* p, int i, bool isb){
  if (isb) { A = *(const uint4*)((const u16*)p + i); }
  else { A = *(const uint4*)((const float*)p + i);
         B = *(const uint4*)((const float*)p + i + 4); }
}
__device__ __forceinline__ void st8(u16* dst, const uint4& A, const uint4& B, bool isb){
  if (isb) { *(uint4*)dst = A; }
  else {
    const float* a = (const float*)&A; const float* b = (const float*)&B;
    dst[0]=f2bf(a[0]); dst[1]=f2bf(a[1]); dst[2]=f2bf(a[2]); dst[3]=f2bf(a[3]);
    dst[4]=f2bf(b[0]); dst[5]=f2bf(b[1]); dst[6]=f2bf(b[2]); dst[7]=f2bf(b[3]);
  }
}
__device__ __forceinline__ float c8(const float* __restrict__ p, int i, int stride){
  float s = 0.f;
  #pragma unroll
  for (int k = 0; k < 8; k++) s += p[i + k*stride];
  return s;
}
// LDS-only barrier: drains ds ops for cross-wave visibility but leaves global
// (prefetch) loads in flight.
__device__ __forceinline__ void bar(){ asm volatile("s_waitcnt lgkmcnt(0)\n\ts_barrier" ::: "memory"); }
// max across each 16-lane DPP row via rotations (VALU-speed, no LDS pipe)
#define RORMAX(x, ctrl) fmaxf((x), __int_as_float(__builtin_amdgcn_update_dpp( \
    __float_as_int(x), __float_as_int(x), (ctrl), 0xF, 0xF, false)))
#define MFMA16(a,b,c) __builtin_amdgcn_mfma_f32_16x16x32_bf16((a),(b),(c),0,0,0)

// ---------------------------------------------------------------------------
// cos/sin table + (block 0) dtype detection. Separate again (R10): fusion
// with proj muddied counters and forced a per-proj-block dtype-detect
// preamble; fusion was only worth ~1-3us. Visibility > micro-fusion.
// ---------------------------------------------------------------------------
__global__ __launch_bounds__(256) void ctab_kernel(const u16* __restrict__ h,
                                                   int* __restrict__ flag,
                                                   float2* __restrict__ ctab) {
  int tid = threadIdx.x;
  if (blockIdx.x == 0) {                          // dtype detect: bf16 vs f32
    int cnt = 0;
    for (int i = tid; i < 4096; i += 256) {
      int e = (h[i] >> 7) & 0xFF;
      cnt += (e >= 116 && e <= 132) ? 1 : 0;      // |x| in [2^-11, 2^5]
    }
    __shared__ int sh[256];
    sh[tid] = cnt; __syncthreads();
    for (int s = 128; s > 0; s >>= 1) { if (tid < s) sh[tid] += sh[tid + s]; __syncthreads(); }
    if (tid == 0) flag[0] = (sh[0] >= 3100) ? 1 : 0;
  }
  int idx = blockIdx.x * 256 + tid;               // 258048 exact
  int dm = idx & 63, t = idx >> 6;
  float f = exp2f(-(float)dm * (13.287712379549449f / 64.0f));
  float ang = (float)t * f;
  float s, c;
  sincosf(ang, &s, &c);
  ctab[idx] = make_float2(c, s);
}

// ---------------------------------------------------------------------------
// Split-K projection: partial = X[64][512] . W^T (used for QKV and Wo).
// 64-col tiles + register-prefetch pipeline: iter k+1's global loads issue
// before iter k's MFMA and stay in flight across the lgkm-only bar().
// Plain launch_bounds — do NOT pin min-waves (spill hazard, see attn note).
// ---------------------------------------------------------------------------
__global__ __launch_bounds__(256) void proj_kernel(
    const void* __restrict__ X, const void* __restrict__ Wa,
    const void* __restrict__ Wb, const void* __restrict__ Wc,
    float* __restrict__ out32, int Na, int Nb, int ostride,
    const int* __restrict__ flagp, int x_dyn)
{
  bool fbf = (*flagp != 0);
  bool xbf = x_dyn ? fbf : true;
  int n0 = blockIdx.x * 64;
  int ks0 = blockIdx.y * 512;
  const void* W; int wr0;
  if (n0 < Na)           { W = Wa; wr0 = n0; }
  else if (n0 < Na + Nb) { W = Wb; wr0 = n0 - Na; }
  else                   { W = Wc; wr0 = n0 - Na - Nb; }

  __shared__ u16 Xs[64][136];
  __shared__ u16 Ws[64][136];
  int tid = threadIdx.x;
  int wv = tid >> 6, lane = tid & 63, lr = lane & 15, lq = lane >> 4;
  f32x4 zf = {0.f,0.f,0.f,0.f};
  f32x4 acc[4] = {zf, zf, zf, zf};

  uint4 xa[4], xb[4], wa[4], wb[4];
  #pragma unroll
  for (int s = 0; s < 4; s++) {
    int e = s * 256 + tid, row = e >> 4, c8i = e & 15;
    pre8(xa[s], xb[s], X, row * 4096 + ks0 + c8i * 8, xbf);
    pre8(wa[s], wb[s], W, (wr0 + row) * 4096 + ks0 + c8i * 8, fbf);
  }
  #pragma unroll 1
  for (int ki = 0; ki < 4; ki++) {
    bar();
    #pragma unroll
    for (int s = 0; s < 4; s++) {
      int e = s * 256 + tid, row = e >> 4, c8i = e & 15;
      st8(&Xs[row][c8i * 8], xa[s], xb[s], xbf);
      st8(&Ws[row][c8i * 8], wa[s], wb[s], fbf);
    }
    if (ki < 3) {
      int k0 = ks0 + (ki + 1) * 128;
      #pragma unroll
      for (int s = 0; s < 4; s++) {
        int e = s * 256 + tid, row = e >> 4, c8i = e & 15;
        pre8(xa[s], xb[s], X, row * 4096 + k0 + c8i * 8, xbf);
        pre8(wa[s], wb[s], W, (wr0 + row) * 4096 + k0 + c8i * 8, fbf);
      }
    }
    bar();
    #pragma unroll
    for (int ks = 0; ks < 4; ks++) {
      bf16x8 af = *(const bf16x8*)&Xs[wv * 16 + lr][ks * 32 + lq * 8];
      #pragma unroll
      for (int nt = 0; nt < 4; nt++) {
        bf16x8 bv = *(const bf16x8*)&Ws[nt * 16 + lr][ks * 32 + lq * 8];
        acc[nt] = MFMA16(af, bv, acc[nt]);
      }
    }
  }
  float* outp = out32 + (size_t)blockIdx.y * 64 * ostride;
  #pragma unroll
  for (int nt = 0; nt < 4; nt++)
    #pragma unroll
    for (int r = 0; r < 4; r++)
      outp[(wv * 16 + lq * 4 + r) * ostride + n0 + nt * 16 + lr] = acc[nt][r];
}

// ---------------------------------------------------------------------------
// Prep: RoPE'd Q [bh][32][128], RoPE'd full-K [bh][64][128], V_full^T [bh][128][64]
// R10: transpose blocks moved to the FRONT of the grid (0..63) — in R9 they
// were at the end and ran as a 64-block serial tail after 3072 blocks drained.
// ---------------------------------------------------------------------------
__global__ __launch_bounds__(256) void prep_kernel(
    const float* __restrict__ Cq32, const void* __restrict__ kfp, const void* __restrict__ vfp,
    const float2* __restrict__ ctab, const int* __restrict__ flagp,
    u16* __restrict__ qrb, u16* __restrict__ kfullb, u16* __restrict__ vfullT)
{
  __shared__ u16 T[64][130];
  bool isbf = (*flagp != 0);
  int tid = threadIdx.x;
  if (blockIdx.x < 64) {                           // v_full^T, one bh per block
    int bh = blockIdx.x;
    int b = bh >> 3, kvh = bh & 7;
    for (int u = tid; u < 8192; u += 256) {        // phase A: [t][d] coalesced
      int t = u >> 7, d = u & 127;
      float x;
      if (t < 56) x = ldf(vfp, (bh * 56 + t) * 128 + d, isbf);
      else        x = c8(Cq32, (b * 8 + t - 56) * 6144 + 5120 + kvh * 128 + d, 393216);
      T[t][d] = f2bf(x);
    }
    __syncthreads();
    for (int u = tid; u < 8192; u += 256) {        // phase B: [d][t] contiguous
      int d = u >> 6, t = u & 63;
      vfullT[bh * 8192 + u] = T[t][d];
    }
  } else {
    int idx = (blockIdx.x - 64) * 256 + tid;
    if (idx < 262144) {                            // qr
      int d = idx & 127, row = (idx >> 7) & 31, bh = idx >> 12;
      int b = bh >> 3, kvh = bh & 7, g = row >> 3, qp = row & 7;
      int tok = b * 8 + qp, h = kvh * 4 + g;
      float x  = c8(Cq32, tok * 6144 + h * 128 + d, 393216);
      float x2 = c8(Cq32, tok * 6144 + h * 128 + (d ^ 64), 393216);
      float2 cs = ctab[(4024 + qp) * 64 + (d & 63)];
      float sgn = (d < 64) ? -1.f : 1.f;
      qrb[idx] = f2bf(x * cs.x + sgn * (x2 * cs.y));
    } else {                                       // k_full roped, pos = 3968+t
      int j = idx - 262144;
      int d = j & 127, t = (j >> 7) & 63, bh = j >> 13;
      int b = bh >> 3, kvh = bh & 7;
      float x, x2;
      if (t < 56) {
        x  = ldf(kfp, (bh * 56 + t) * 128 + d, isbf);
        x2 = ldf(kfp, (bh * 56 + t) * 128 + (d ^ 64), isbf);
      } else {
        int tok = b * 8 + (t - 56);
        x  = c8(Cq32, tok * 6144 + 4096 + kvh * 128 + d, 393216);
        x2 = c8(Cq32, tok * 6144 + 4096 + kvh * 128 + (d ^ 64), 393216);
      }
      float2 cs = ctab[(3968 + t) * 64 + (d & 63)];
      float sgn = (d < 64) ? -1.f : 1.f;
      kfullb[j] = f2bf(x * cs.x + sgn * (x2 * cs.y));
    }
  }
}

// ---------------------------------------------------------------------------
// Online-flash attention, 64-key chunks, 4 per block, 2-phase software pipeline.
// Grid (64 bh, 16 grp). Chunks 0..61 quantized; 62 full; 63 skipped.
//   P1: S(c)=QK MFMA + DPP row-max + pmax write  ||  PV(c-1) MFMA + ones-MFMA
//   P2: alpha/exp + Pl(c) write + V-stage(c) + K-stage(c+1) + reg prefetch
// R8: KDEQ ctab loads replaced by angle-addition recurrence (4 FMA/step),
// csd = ctab[64+lane] loaded once; ii=0 seeds prefetched in KLOAD. KDEQ is
// pure VALU+ds_write. (R9: attn dropped out of top-5, <49.5us.)
// NOTE: plain __launch_bounds__(256). (256,4) capped VGPR at 64 and spilled
// ~140MB to scratch (R2). Keep the allocator free.
// NOTE: no fused combine — R6's completion-counter + __threadfence cost +147us.
// ---------------------------------------------------------------------------
__global__ __launch_bounds__(256) void attn_kernel(
    const int* __restrict__ kqw, const void* __restrict__ ksc, const void* __restrict__ kmn,
    const int* __restrict__ vqw, const void* __restrict__ vsc, const void* __restrict__ vmn,
    const u16* __restrict__ qrb, const u16* __restrict__ kfullb, const u16* __restrict__ vfullT,
    const float2* __restrict__ ctab, const int* __restrict__ flagp,
    u16* __restrict__ Opart, float* __restrict__ ml)
{
  bool isbf = (*flagp != 0);
  int bh = blockIdx.x, grp = blockIdx.y;
  int tid = threadIdx.x;
  int c0 = grp * 4;
  int N = (grp == 15) ? 3 : 4;                     // grp 15: chunks 60,61,62(full)

  __shared__ __align__(16) unsigned char L[37120];
  u16* Kt = (u16*)L;                               // [64 t][128 d] swz  16384 B
  u16* Vt = (u16*)(L + 16384);                     // [128 d][64 t] swz  16384 B
  u16* Pt = (u16*)(L + 32768);                     // [32 q][64 k] swz    4096 B
  float* pmax = (float*)(L + 36864);               // [4][16]

  int wv = tid >> 6, lane = tid & 63, lr = lane & 15, lq = lane >> 4;
  int mt = wv & 1, nh = wv >> 1;
  int sx = (lr & 7) << 3;                          // read-side XOR (row&7 == lr&7)

  const int* kq_lo = kqw + (bh * 128 + lane) * 496;
  const int* kq_hi = kq_lo + 64 * 496;
  int klo = (bh * 128 + lane) * 124;
  int khi = klo + 64 * 124;
  const int* vqp = vqw + (bh * 3968 + lane) * 16 + wv * 4;
  int voff = (bh * 3968 + lane) * 4 + wv;

  bf16x8 qa[4];
  #pragma unroll
  for (int ks = 0; ks < 4; ks++)
    qa[ks] = *(const bf16x8*)&qrb[(bh * 32 + mt * 16 + lr) * 128 + ks * 32 + lq * 8];
  bf16x8 onev;
  #pragma unroll
  for (int j2 = 0; j2 < 8; j2++) onev[j2] = (short)0x3F80;   // bf16 1.0
  float2 csd = ctab[64 + lane];                    // per-lane unit-step rotor

  float m_prev[4], l_run[4], alpha[4], mx[4];
  f32x4 zf = {0.f,0.f,0.f,0.f};
  f32x4 oacc[4] = {zf, zf, zf, zf};
  f32x4 sacc[2];
  #pragma unroll
  for (int r = 0; r < 4; r++) { m_prev[r] = -INFINITY; l_run[r] = 0.f; }

  // prefetch registers
  unsigned kwl[2], kwh[2];
  float2 ksl, kml, ksh, kmh;
  float2 ct0[2];
  uint4 vw; float vs, vm;

#define KLOAD(cn) do { \
    kwl[0] = kq_lo[(cn)*8 + wv]; kwl[1] = kq_lo[(cn)*8 + wv + 4]; \
    kwh[0] = kq_hi[(cn)*8 + wv]; kwh[1] = kq_hi[(cn)*8 + wv + 4]; \
    ksl = ld2(ksc, klo + (cn)*2, isbf); kml = ld2(kmn, klo + (cn)*2, isbf); \
    ksh = ld2(ksc, khi + (cn)*2, isbf); kmh = ld2(kmn, khi + (cn)*2, isbf); \
    ct0[0] = ctab[((cn)*64 + wv*8)*64 + lane]; \
    ct0[1] = ctab[((cn)*64 + (wv+4)*8)*64 + lane]; } while(0)
#define VLOAD(cn) do { \
    vw = *(const uint4*)(vqp + (cn)*1024); \
    vs = ldf(vsc, voff + (cn)*256, isbf); vm = ldf(vmn, voff + (cn)*256, isbf); } while(0)
#define KDEQ(cn) do { \
    _Pragma("unroll") \
    for (int it = 0; it < 2; it++) { \
      int w = wv + 4 * it; \
      unsigned w1 = kwl[it], w2 = kwh[it]; \
      float sc1 = it ? ksl.y : ksl.x, m1 = it ? kml.y : kml.x; \
      float sc2 = it ? ksh.y : ksh.x, m2 = it ? kmh.y : kmh.x; \
      float2 cs = ct0[it]; \
      _Pragma("unroll") \
      for (int ii = 0; ii < 8; ii++) { \
        float v1 = (float)((w1 >> (4 * ii)) & 15u) * sc1 + m1; \
        float v2 = (float)((w2 >> (4 * ii)) & 15u) * sc2 + m2; \
        int t = w * 8 + ii; \
        Kt[(t * 128 + lane)      ^ ((t & 7) << 3)] = f2bf(v1 * cs.x - v2 * cs.y); \
        Kt[(t * 128 + lane + 64) ^ ((t & 7) << 3)] = f2bf(v2 * cs.x + v1 * cs.y); \
        float nx = cs.x * csd.x - cs.y * csd.y; \
        cs.y = cs.y * csd.x + cs.x * csd.y; \
        cs.x = nx; \
      } \
    } } while(0)
#define PVSTEP() do { \
    f32x4 pv[4] = {zf, zf, zf, zf}; f32x4 ls = zf; \
    _Pragma("unroll") \
    for (int ks = 0; ks < 2; ks++) { \
      bf16x8 af = *(const bf16x8*)&Pt[((mt*16 + lr)*64 + ks*32 + lq*8) ^ sx]; \
      ls = MFMA16(af, onev, ls); \
      _Pragma("unroll") \
      for (int nt = 0; nt < 4; nt++) { \
        bf16x8 bv = *(const bf16x8*)&Vt[((nh*64 + nt*16 + lr)*64 + ks*32 + lq*8) ^ sx]; \
        pv[nt] = MFMA16(af, bv, pv[nt]); \
      } \
    } \
    _Pragma("unroll") \
    for (int r = 0; r < 4; r++) { \
      l_run[r] = l_run[r] * alpha[r] + ls[r]; \
      _Pragma("unroll") \
      for (int nt = 0; nt < 4; nt++) \
        oacc[nt][r] = oacc[nt][r] * alpha[r] + pv[nt][r]; \
    } } while(0)

  // ---- prologue: K(c0) -> Kt; refill K regs with c0+1 (always quant) ----
  KLOAD(c0);
  VLOAD(c0);
  KDEQ(c0);
  KLOAD(c0 + 1);
  bar();

  for (int i = 0; i < N; i++) {
    int c = c0 + i;
    // ================= P1: S(c) + PV(c-1) =================
    f32x4 sa0 = zf, sa1 = zf;
    #pragma unroll
    for (int ks = 0; ks < 4; ks++) {
      bf16x8 b0 = *(const bf16x8*)&Kt[((nh*32 + lr)*128      + ks*32 + lq*8) ^ sx];
      bf16x8 b1 = *(const bf16x8*)&Kt[((nh*32 + 16 + lr)*128 + ks*32 + lq*8) ^ sx];
      sa0 = MFMA16(qa[ks], b0, sa0);
      sa1 = MFMA16(qa[ks], b1, sa1);
    }
    if (i > 0) PVSTEP();                           // uses alpha from P2(i-1)
    #pragma unroll
    for (int r = 0; r < 4; r++) {
      sa0[r] *= 0.08838834764831845f;
      sa1[r] *= 0.08838834764831845f;
      float m0 = fmaxf(sa0[r], sa1[r]);
      m0 = RORMAX(m0, 0x128);                      // row_ror:8
      m0 = RORMAX(m0, 0x124);                      // row_ror:4
      m0 = RORMAX(m0, 0x122);                      // row_ror:2
      m0 = RORMAX(m0, 0x121);                      // row_ror:1
      mx[r] = m0;
    }
    if (lr == 0) {
      #pragma unroll
      for (int r = 0; r < 4; r++) pmax[wv * 16 + lq * 4 + r] = mx[r];
    }
    sacc[0] = sa0; sacc[1] = sa1;
    bar();
    // ================= P2: softmax + stage tiles ==========
    #pragma unroll
    for (int r = 0; r < 4; r++) {
      float cm = fmaxf(mx[r], pmax[(wv ^ 2) * 16 + lq * 4 + r]);
      float mn2 = fmaxf(m_prev[r], cm);
      alpha[r] = __expf(m_prev[r] - mn2);          // 0 on first chunk
      m_prev[r] = mn2;
    }
    #pragma unroll
    for (int nt = 0; nt < 2; nt++) {
      #pragma unroll
      for (int r = 0; r < 4; r++) {
        float p = __expf(sacc[nt][r] - m_prev[r]);
        int q = mt * 16 + lq * 4 + r, k = nh * 32 + nt * 16 + lr;
        Pt[(q * 64 + k) ^ ((q & 7) << 3)] = f2bf(p);
      }
    }
    // V-stage(c)
    if (c != 62) {
      unsigned wds[4] = {vw.x, vw.y, vw.z, vw.w};
      #pragma unroll
      for (int it = 0; it < 4; it++) {
        unsigned wd = wds[it];
        #pragma unroll
        for (int ii = 0; ii < 8; ii++) {
          int d = (wv * 4 + it) * 8 + ii;
          Vt[(d * 64 + lane) ^ ((d & 7) << 3)] = f2bf((float)((wd >> (4 * ii)) & 15u) * vs + vm);
        }
      }
    } else {
      for (int u = tid; u < 1024; u += 256) {
        int dd = u >> 3, t8 = u & 7;
        *(uint4*)&Vt[(dd * 64 + t8 * 8) ^ ((dd & 7) << 3)] =
            *(const uint4*)&vfullT[(bh * 128 + dd) * 64 + t8 * 8];
      }
    }
    // K-stage(c+1)
    if (i + 1 < N) {
      if (c + 1 == 62) {
        for (int u = tid; u < 1024; u += 256) {
          int row = u >> 4, cc = u & 15;
          *(uint4*)&Kt[(row * 128 + cc * 8) ^ ((row & 7) << 3)] =
              *(const uint4*)&kfullb[(bh * 64 + row) * 128 + cc * 8];
        }
      } else {
        KDEQ(c + 1);
      }
    }
    // register prefetch for the NEXT P2 (flight spans P1(i+1))
    if (i + 2 < N && c + 2 < 62) KLOAD(c + 2);
    if (i + 1 < N && c + 1 < 62) VLOAD(c + 1);
    bar();
  }
  // ---- epilogue: PV of last chunk ----
  PVSTEP();

  u16* Ob = Opart + (size_t)((bh * 16 + grp) * 32) * 128;
  #pragma unroll
  for (int nt = 0; nt < 4; nt++)
    #pragma unroll
    for (int r = 0; r < 4; r++)
      Ob[(mt * 16 + lq * 4 + r) * 128 + nh * 64 + nt * 16 + lr] = f2bf(oacc[nt][r]);
  if (wv < 2 && lr == 0) {
    #pragma unroll
    for (int r = 0; r < 4; r++) {
      ml[((bh * 16 + grp) * 32 + mt * 16 + lq * 4 + r) * 2 + 0] = m_prev[r];
      ml[((bh * 16 + grp) * 32 + mt * 16 + lq * 4 + r) * 2 + 1] = l_run[r];
    }
  }
#undef KLOAD
#undef VLOAD
#undef KDEQ
#undef PVSTEP
}

// ---------------------------------------------------------------------------
// Combine 16 group partials per bh. Grid (64, 4 d-quarters).
// ---------------------------------------------------------------------------
__global__ __launch_bounds__(256) void combine_kernel(
    const u16* __restrict__ Opart, const float* __restrict__ ml, u16* __restrict__ attn_out)
{
  int bh = blockIdx.x, dq = blockIdx.y, tid = threadIdx.x;
  __shared__ float Wg[16][33];
  __shared__ float Ls[32];
  if (tid < 32) {
    int row = tid;
    float M = -INFINITY;
    for (int g = 0; g < 16; g++)
      M = fmaxf(M, ml[((bh * 16 + g) * 32 + row) * 2]);
    float Lacc = 0.f;
    for (int g = 0; g < 16; g++) {
      float m = ml[((bh * 16 + g) * 32 + row) * 2];
      float l = ml[((bh * 16 + g) * 32 + row) * 2 + 1];
      float w = __expf(m - M);
      Wg[g][row] = w;
      Lacc += l * w;
    }
    Ls[row] = Lacc;
  }
  __syncthreads();
  int row = tid >> 3, ds = tid & 7;
  int d0 = dq * 32 + ds * 4;
  float a0 = 0.f, a1 = 0.f, a2 = 0.f, a3 = 0.f;
  for (int g = 0; g < 16; g++) {
    float w = Wg[g][row];
    const u16* p = Opart + (size_t)((bh * 16 + g) * 32 + row) * 128 + d0;
    uint2 v = *(const uint2*)p;
    const u16* h = (const u16*)&v;
    a0 += w * b2f(h[0]); a1 += w * b2f(h[1]); a2 += w * b2f(h[2]); a3 += w * b2f(h[3]);
  }
  float inv = 1.0f / Ls[row];
  int b = bh >> 3, kvh = bh & 7, hg = row >> 3, qp = row & 7;
  u16* dst = attn_out + (size_t)(b * 8 + qp) * 4096 + (kvh * 4 + hg) * 128 + d0;
  dst[0] = f2bf(a0 * inv); dst[1] = f2bf(a1 * inv);
  dst[2] = f2bf(a2 * inv); dst[3] = f2bf(a3 * inv);
}

// ---------------------------------------------------------------------------
// Sum 8 Wo K-split partials, emit final output in detected dtype.
// ---------------------------------------------------------------------------
__global__ __launch_bounds__(256) void cast_kernel(
    const float* __restrict__ O32, const int* __restrict__ flagp, void* __restrict__ out)
{
  int i = blockIdx.x * 256 + threadIdx.x;          // 262144 exact
  float v = c8(O32, i, 262144);
  if (*flagp) ((u16*)out)[i] = f2bf(v);
  else        ((float*)out)[i] = v;
}

// ---------------------------------------------------------------------------
extern "C" void kernel_launch(void* const* d_in, const int* in_sizes, int n_in,
                              void* d_out, int out_size, void* d_ws, size_t ws_size,
                              hipStream_t stream)
{
  const void* hidden = d_in[0];
  const void* Wq  = d_in[1];
  const void* Wk  = d_in[2];
  const void* Wv  = d_in[3];
  const void* Wo  = d_in[4];
  const int*  kqw = (const int*)d_in[5];
  const void* ksc = d_in[6];
  const void* kmn = d_in[7];
  const void* kfp = d_in[8];
  const int*  vqw = (const int*)d_in[9];
  const void* vsc = d_in[10];
  const void* vmn = d_in[11];
  const void* vfp = d_in[12];

  char* ws = (char*)d_ws;
  int*    flag     = (int*)(ws);                    //        256
  float2* ctab     = (float2*)(ws + 256);           //  2,064,384
  float*  Cq32     = (float*)(ws + 2064640);        // regionA 16,777,216:
  u16*    Opart    = (u16*)(ws + 2064640);          //   Cq32 12.6MB / Opart 8.4MB / O32 8.4MB
  float*  O32      = (float*)(ws + 2064640);        //   (pairwise-disjoint lifetimes)
  u16*    qrb      = (u16*)(ws + 18841856);         //    524,288 (attn_out overlays)
  u16*    attn_out = qrb;
  u16*    kfullb   = (u16*)(ws + 19366144);         //  1,048,576
  u16*    vfullT   = (u16*)(ws + 20414720);         //  1,048,576
  float*  ml       = (float*)(ws + 21463296);       //    524,288 (uses 262,144)

  ctab_kernel<<<1008, 256, 0, stream>>>((const u16*)hidden, flag, ctab);
  proj_kernel<<<dim3(96, 8), 256, 0, stream>>>(hidden, Wq, Wk, Wv, Cq32, 4096, 1024, 6144, flag, 1);
  prep_kernel<<<3136, 256, 0, stream>>>(Cq32, kfp, vfp, ctab, flag, qrb, kfullb, vfullT);
  attn_kernel<<<dim3(64, 16), 256, 0, stream>>>(kqw, ksc, kmn, vqw, vsc, vmn,
                                                qrb, kfullb, vfullT, ctab, flag, Opart, ml);
  combine_kernel<<<dim3(64, 4), 256, 0, stream>>>(Opart, ml, attn_out);
  proj_kernel<<<dim3(64, 8), 256, 0, stream>>>(attn_out, Wo, Wo, Wo, O32, 4096, 0, 4096, flag, 0);
  cast_kernel<<<1024, 256, 0, stream>>>(O32, flag, d_out);
}

// Round 11
// 285.516 us; speedup vs baseline: 1.0472x; 1.0342x over previous
//
#include <hip/hip_runtime.h>

typedef unsigned short u16;
typedef short bf16x8 __attribute__((ext_vector_type(8)));
typedef float f32x4 __attribute__((ext_vector_type(4)));

__device__ __forceinline__ float b2f(u16 u){ return __uint_as_float(((unsigned)u)<<16); }
__device__ __forceinline__ u16 f2bf(float f){ return (u16)((__float_as_uint(f)+0x8000u)>>16); }
__device__ __forceinline__ float ldf(const void* p, int i, bool isbf){
  return isbf ? b2f(((const u16*)p)[i]) : ((const float*)p)[i];
}
__device__ __forceinline__ float2 ld2(const void* p, int i, bool isbf){
  if (isbf) { unsigned u = *(const unsigned*)((const u16*)p + i);
              return make_float2(b2f((u16)(u & 0xffffu)), b2f((u16)(u >> 16))); }
  return *(const float2*)((const float*)p + i);
}
// prefetch-to-regs / store-to-LDS pair for the proj staging pipeline
__device__ __forceinline__ void pre8(uint4& A, uint4& B, const void* p, int i, bool isb){
  if (isb) { A = *(const uint4*)((const u16*)p + i); }
  else { A = *(const uint4*)((const float*)p + i);
         B = *(const uint4*)((const float*)p + i + 4); }
}
__device__ __forceinline__ void st8(u16* dst, const uint4& A, const uint4& B, bool isb){
  if (isb) { *(uint4*)dst = A; }
  else {
    const float* a = (const float*)&A; const float* b = (const float*)&B;
    dst[0]=f2bf(a[0]); dst[1]=f2bf(a[1]); dst[2]=f2bf(a[2]); dst[3]=f2bf(a[3]);
    dst[4]=f2bf(b[0]); dst[5]=f2bf(b[1]); dst[6]=f2bf(b[2]); dst[7]=f2bf(b[3]);
  }
}
__device__ __forceinline__ float c8(const float* __restrict__ p, int i, int stride){
  float s = 0.f;
  #pragma unroll
  for (int k = 0; k < 8; k++) s += p[i + k*stride];
  return s;
}
// LDS-only barrier: drains ds ops for cross-wave visibility but leaves global
// (prefetch) loads in flight.
__device__ __forceinline__ void bar(){ asm volatile("s_waitcnt lgkmcnt(0)\n\ts_barrier" ::: "memory"); }
// max across each 16-lane DPP row via rotations (VALU-speed, no LDS pipe)
#define RORMAX(x, ctrl) fmaxf((x), __int_as_float(__builtin_amdgcn_update_dpp( \
    __float_as_int(x), __float_as_int(x), (ctrl), 0xF, 0xF, false)))
#define MFMA16(a,b,c) __builtin_amdgcn_mfma_f32_16x16x32_bf16((a),(b),(c),0,0,0)

// ---------------------------------------------------------------------------
// Fused: cos/sin table (+flag) AND QKV split-K projection. (R7 config — best
// measured total 290.6. R10's un-fused split did not beat it.)
// Blocks 0..1007: ctab. Blocks 1008..1775: proj (96 n-blocks x 8 k-slices).
// Proj blocks recompute the dtype flag locally from `hidden`.
// NOTE (R6 lesson): no cross-block completion fusion — __threadfence()
// completion-counter cost +147us (per-block device-scope fence).
// ---------------------------------------------------------------------------
__global__ __launch_bounds__(256) void ctab_proj_kernel(
    const u16* __restrict__ h, int* __restrict__ flag, float2* __restrict__ ctab,
    const void* __restrict__ Wa, const void* __restrict__ Wb, const void* __restrict__ Wc,
    float* __restrict__ out32)
{
  __shared__ __align__(16) u16 XW[2][64][136];     // proj tiles; ctab reuses as int[]
  int tid = threadIdx.x;

  if (blockIdx.x < 1008) {                         // ================= ctab part
    if (blockIdx.x == 0) {                         // dtype detect
      int c = 0;
      for (int i = tid; i < 4096; i += 256) {
        int e = (h[i] >> 7) & 0xFF;
        c += (e >= 116 && e <= 132) ? 1 : 0;
      }
      int* sh = (int*)XW;
      sh[tid] = c; __syncthreads();
      for (int s = 128; s > 0; s >>= 1) { if (tid < s) sh[tid] += sh[tid + s]; __syncthreads(); }
      if (tid == 0) flag[0] = (sh[0] >= 3100) ? 1 : 0;
    }
    int idx = blockIdx.x * 256 + tid;              // 258048 exact
    int dm = idx & 63, t = idx >> 6;
    float f = exp2f(-(float)dm * (13.287712379549449f / 64.0f));
    float ang = (float)t * f;
    float s, c;
    sincosf(ang, &s, &c);
    ctab[idx] = make_float2(c, s);
    return;
  }
  // ======================================================= proj part
  int bx = blockIdx.x - 1008;
  int n0 = (bx % 96) * 64;
  int ks0 = (bx / 96) * 512;
  // local dtype detection (same result in every block)
  int tot;
  {
    int c = 0;
    for (int i = tid; i < 4096; i += 256) {
      int e = (h[i] >> 7) & 0xFF;
      c += (e >= 116 && e <= 132) ? 1 : 0;
    }
    int* sh = (int*)XW;
    sh[tid] = c; __syncthreads();
    for (int s = 128; s > 0; s >>= 1) { if (tid < s) sh[tid] += sh[tid + s]; __syncthreads(); }
    tot = sh[0];
    __syncthreads();                               // sh dead before tile staging
  }
  bool fbf = (tot >= 3100);
  bool xbf = fbf;                                  // x = hidden (dynamic dtype)
  const void* X = h;
  const void* W; int wr0;
  if (n0 < 4096)      { W = Wa; wr0 = n0; }
  else if (n0 < 5120) { W = Wb; wr0 = n0 - 4096; }
  else                { W = Wc; wr0 = n0 - 5120; }

  int wv = tid >> 6, lane = tid & 63, lr = lane & 15, lq = lane >> 4;
  f32x4 zf = {0.f,0.f,0.f,0.f};
  f32x4 acc[4] = {zf, zf, zf, zf};

  uint4 xa[4], xb[4], wa[4], wb[4];                // one prefetch generation
  #pragma unroll
  for (int s = 0; s < 4; s++) {
    int e = s * 256 + tid, row = e >> 4, c8i = e & 15;
    pre8(xa[s], xb[s], X, row * 4096 + ks0 + c8i * 8, xbf);
    pre8(wa[s], wb[s], W, (wr0 + row) * 4096 + ks0 + c8i * 8, fbf);
  }
  #pragma unroll 1
  for (int ki = 0; ki < 4; ki++) {
    bar();                                         // prev MFMA reads done
    #pragma unroll
    for (int s = 0; s < 4; s++) {
      int e = s * 256 + tid, row = e >> 4, c8i = e & 15;
      st8(&XW[0][row][c8i * 8], xa[s], xb[s], xbf);
      st8(&XW[1][row][c8i * 8], wa[s], wb[s], fbf);
    }
    if (ki < 3) {                                  // prefetch next k-slice
      int k0 = ks0 + (ki + 1) * 128;
      #pragma unroll
      for (int s = 0; s < 4; s++) {
        int e = s * 256 + tid, row = e >> 4, c8i = e & 15;
        pre8(xa[s], xb[s], X, row * 4096 + k0 + c8i * 8, xbf);
        pre8(wa[s], wb[s], W, (wr0 + row) * 4096 + k0 + c8i * 8, fbf);
      }
    }
    bar();                                         // LDS tiles visible
    #pragma unroll
    for (int ks = 0; ks < 4; ks++) {
      bf16x8 af = *(const bf16x8*)&XW[0][wv * 16 + lr][ks * 32 + lq * 8];
      #pragma unroll
      for (int nt = 0; nt < 4; nt++) {
        bf16x8 bv = *(const bf16x8*)&XW[1][nt * 16 + lr][ks * 32 + lq * 8];
        acc[nt] = MFMA16(af, bv, acc[nt]);
      }
    }
  }
  float* outp = out32 + (size_t)(bx / 96) * 64 * 6144;
  #pragma unroll
  for (int nt = 0; nt < 4; nt++)
    #pragma unroll
    for (int r = 0; r < 4; r++)
      outp[(wv * 16 + lq * 4 + r) * 6144 + n0 + nt * 16 + lr] = acc[nt][r];
}

// ---------------------------------------------------------------------------
// Split-K projection (standalone, used for Wo): partial = X[64][512] . W^T
// ---------------------------------------------------------------------------
__global__ __launch_bounds__(256) void proj_kernel(
    const void* __restrict__ X, const void* __restrict__ Wa,
    const void* __restrict__ Wb, const void* __restrict__ Wc,
    float* __restrict__ out32, int Na, int Nb, int ostride,
    const int* __restrict__ flagp, int x_dyn)
{
  bool fbf = (*flagp != 0);
  bool xbf = x_dyn ? fbf : true;
  int n0 = blockIdx.x * 64;
  int ks0 = blockIdx.y * 512;
  const void* W; int wr0;
  if (n0 < Na)           { W = Wa; wr0 = n0; }
  else if (n0 < Na + Nb) { W = Wb; wr0 = n0 - Na; }
  else                   { W = Wc; wr0 = n0 - Na - Nb; }

  __shared__ u16 Xs[64][136];
  __shared__ u16 Ws[64][136];
  int tid = threadIdx.x;
  int wv = tid >> 6, lane = tid & 63, lr = lane & 15, lq = lane >> 4;
  f32x4 zf = {0.f,0.f,0.f,0.f};
  f32x4 acc[4] = {zf, zf, zf, zf};

  uint4 xa[4], xb[4], wa[4], wb[4];
  #pragma unroll
  for (int s = 0; s < 4; s++) {
    int e = s * 256 + tid, row = e >> 4, c8i = e & 15;
    pre8(xa[s], xb[s], X, row * 4096 + ks0 + c8i * 8, xbf);
    pre8(wa[s], wb[s], W, (wr0 + row) * 4096 + ks0 + c8i * 8, fbf);
  }
  #pragma unroll 1
  for (int ki = 0; ki < 4; ki++) {
    bar();
    #pragma unroll
    for (int s = 0; s < 4; s++) {
      int e = s * 256 + tid, row = e >> 4, c8i = e & 15;
      st8(&Xs[row][c8i * 8], xa[s], xb[s], xbf);
      st8(&Ws[row][c8i * 8], wa[s], wb[s], fbf);
    }
    if (ki < 3) {
      int k0 = ks0 + (ki + 1) * 128;
      #pragma unroll
      for (int s = 0; s < 4; s++) {
        int e = s * 256 + tid, row = e >> 4, c8i = e & 15;
        pre8(xa[s], xb[s], X, row * 4096 + k0 + c8i * 8, xbf);
        pre8(wa[s], wb[s], W, (wr0 + row) * 4096 + k0 + c8i * 8, fbf);
      }
    }
    bar();
    #pragma unroll
    for (int ks = 0; ks < 4; ks++) {
      bf16x8 af = *(const bf16x8*)&Xs[wv * 16 + lr][ks * 32 + lq * 8];
      #pragma unroll
      for (int nt = 0; nt < 4; nt++) {
        bf16x8 bv = *(const bf16x8*)&Ws[nt * 16 + lr][ks * 32 + lq * 8];
        acc[nt] = MFMA16(af, bv, acc[nt]);
      }
    }
  }
  float* outp = out32 + (size_t)blockIdx.y * 64 * ostride;
  #pragma unroll
  for (int nt = 0; nt < 4; nt++)
    #pragma unroll
    for (int r = 0; r < 4; r++)
      outp[(wv * 16 + lq * 4 + r) * ostride + n0 + nt * 16 + lr] = acc[nt][r];
}

// ---------------------------------------------------------------------------
// Prep: RoPE'd Q [bh][32][128], RoPE'd full-K [bh][64][128], V_full^T [bh][128][64]
// R11: reverted to the R7 flat 5120-block form. The R8 "coalesced transpose"
// rebuild REGRESSED ~8-12us: it concentrated the vfullT work into 64 blocks
// with 32-iteration serial dependent-load loops, replacing a fully-parallel
// (TLP-latency-hidden) strided version. Lesson: this kernel is latency-bound
// with ample TLP, not BW-bound — coalescing wasn't the binding constraint.
// ---------------------------------------------------------------------------
__global__ __launch_bounds__(256) void prep_kernel(
    const float* __restrict__ Cq32, const void* __restrict__ kfp, const void* __restrict__ vfp,
    const float2* __restrict__ ctab, const int* __restrict__ flagp,
    u16* __restrict__ qrb, u16* __restrict__ kfullb, u16* __restrict__ vfullT)
{
  bool isbf = (*flagp != 0);
  int idx = blockIdx.x * 256 + threadIdx.x;       // 1,310,720 exact
  if (idx < 262144) {                              // qr
    int d = idx & 127, row = (idx >> 7) & 31, bh = idx >> 12;
    int b = bh >> 3, kvh = bh & 7, g = row >> 3, qp = row & 7;
    int tok = b * 8 + qp, h = kvh * 4 + g;
    float x  = c8(Cq32, tok * 6144 + h * 128 + d, 393216);
    float x2 = c8(Cq32, tok * 6144 + h * 128 + (d ^ 64), 393216);
    float2 cs = ctab[(4024 + qp) * 64 + (d & 63)];
    float sgn = (d < 64) ? -1.f : 1.f;
    qrb[idx] = f2bf(x * cs.x + sgn * (x2 * cs.y));
  } else if (idx < 786432) {                       // k_full roped, pos = 3968+t
    int j = idx - 262144;
    int d = j & 127, t = (j >> 7) & 63, bh = j >> 13;
    int b = bh >> 3, kvh = bh & 7;
    float x, x2;
    if (t < 56) {
      x  = ldf(kfp, (bh * 56 + t) * 128 + d, isbf);
      x2 = ldf(kfp, (bh * 56 + t) * 128 + (d ^ 64), isbf);
    } else {
      int tok = b * 8 + (t - 56);
      x  = c8(Cq32, tok * 6144 + 4096 + kvh * 128 + d, 393216);
      x2 = c8(Cq32, tok * 6144 + 4096 + kvh * 128 + (d ^ 64), 393216);
    }
    float2 cs = ctab[(3968 + t) * 64 + (d & 63)];
    float sgn = (d < 64) ? -1.f : 1.f;
    kfullb[j] = f2bf(x * cs.x + sgn * (x2 * cs.y));
  } else {                                         // v_full transposed [bh][d][t]
    int j = idx - 786432;
    int t = j & 63, d = (j >> 6) & 127, bh = j >> 13;
    int b = bh >> 3, kvh = bh & 7;
    float x;
    if (t < 56) x = ldf(vfp, (bh * 56 + t) * 128 + d, isbf);
    else        x = c8(Cq32, (b * 8 + t - 56) * 6144 + 5120 + kvh * 128 + d, 393216);
    vfullT[j] = f2bf(x);
  }
}

// ---------------------------------------------------------------------------
// Online-flash attention, 64-key chunks, 4 per block, 2-phase software pipeline.
// Grid (64 bh, 16 grp). Chunks 0..61 quantized; 62 full; 63 skipped.
//   P1: S(c)=QK MFMA + DPP row-max + pmax write  ||  PV(c-1) MFMA + ones-MFMA
//   P2: alpha/exp + Pl(c) write + V-stage(c) + K-stage(c+1) + reg prefetch
// KDEQ uses angle-addition recurrence (R8, verified R10: 53.2->46.5us,
// FETCH 34.3->27.0MB): cs(ii+1) = cs(ii)*csd (4 FMA), csd = ctab[64+lane];
// ii=0 seeds prefetched in KLOAD. KDEQ is pure VALU+ds_write.
// NOTE: plain __launch_bounds__(256) — (256,4) pinned VGPR 64 and spilled
// ~140MB (R2). NOTE: no fused combine — R6 cost +147us.
// ---------------------------------------------------------------------------
__global__ __launch_bounds__(256) void attn_kernel(
    const int* __restrict__ kqw, const void* __restrict__ ksc, const void* __restrict__ kmn,
    const int* __restrict__ vqw, const void* __restrict__ vsc, const void* __restrict__ vmn,
    const u16* __restrict__ qrb, const u16* __restrict__ kfullb, const u16* __restrict__ vfullT,
    const float2* __restrict__ ctab, const int* __restrict__ flagp,
    u16* __restrict__ Opart, float* __restrict__ ml)
{
  bool isbf = (*flagp != 0);
  int bh = blockIdx.x, grp = blockIdx.y;
  int tid = threadIdx.x;
  int c0 = grp * 4;
  int N = (grp == 15) ? 3 : 4;                     // grp 15: chunks 60,61,62(full)

  __shared__ __align__(16) unsigned char L[37120];
  u16* Kt = (u16*)L;                               // [64 t][128 d] swz  16384 B
  u16* Vt = (u16*)(L + 16384);                     // [128 d][64 t] swz  16384 B
  u16* Pt = (u16*)(L + 32768);                     // [32 q][64 k] swz    4096 B
  float* pmax = (float*)(L + 36864);               // [4][16]

  int wv = tid >> 6, lane = tid & 63, lr = lane & 15, lq = lane >> 4;
  int mt = wv & 1, nh = wv >> 1;
  int sx = (lr & 7) << 3;                          // read-side XOR (row&7 == lr&7)

  const int* kq_lo = kqw + (bh * 128 + lane) * 496;
  const int* kq_hi = kq_lo + 64 * 496;
  int klo = (bh * 128 + lane) * 124;
  int khi = klo + 64 * 124;
  const int* vqp = vqw + (bh * 3968 + lane) * 16 + wv * 4;
  int voff = (bh * 3968 + lane) * 4 + wv;

  bf16x8 qa[4];
  #pragma unroll
  for (int ks = 0; ks < 4; ks++)
    qa[ks] = *(const bf16x8*)&qrb[(bh * 32 + mt * 16 + lr) * 128 + ks * 32 + lq * 8];
  bf16x8 onev;
  #pragma unroll
  for (int j2 = 0; j2 < 8; j2++) onev[j2] = (short)0x3F80;   // bf16 1.0
  float2 csd = ctab[64 + lane];                    // per-lane unit-step rotor

  float m_prev[4], l_run[4], alpha[4], mx[4];
  f32x4 zf = {0.f,0.f,0.f,0.f};
  f32x4 oacc[4] = {zf, zf, zf, zf};
  f32x4 sacc[2];
  #pragma unroll
  for (int r = 0; r < 4; r++) { m_prev[r] = -INFINITY; l_run[r] = 0.f; }

  // prefetch registers
  unsigned kwl[2], kwh[2];
  float2 ksl, kml, ksh, kmh;
  float2 ct0[2];
  uint4 vw; float vs, vm;

#define KLOAD(cn) do { \
    kwl[0] = kq_lo[(cn)*8 + wv]; kwl[1] = kq_lo[(cn)*8 + wv + 4]; \
    kwh[0] = kq_hi[(cn)*8 + wv]; kwh[1] = kq_hi[(cn)*8 + wv + 4]; \
    ksl = ld2(ksc, klo + (cn)*2, isbf); kml = ld2(kmn, klo + (cn)*2, isbf); \
    ksh = ld2(ksc, khi + (cn)*2, isbf); kmh = ld2(kmn, khi + (cn)*2, isbf); \
    ct0[0] = ctab[((cn)*64 + wv*8)*64 + lane]; \
    ct0[1] = ctab[((cn)*64 + (wv+4)*8)*64 + lane]; } while(0)
#define VLOAD(cn) do { \
    vw = *(const uint4*)(vqp + (cn)*1024); \
    vs = ldf(vsc, voff + (cn)*256, isbf); vm = ldf(vmn, voff + (cn)*256, isbf); } while(0)
#define KDEQ(cn) do { \
    _Pragma("unroll") \
    for (int it = 0; it < 2; it++) { \
      int w = wv + 4 * it; \
      unsigned w1 = kwl[it], w2 = kwh[it]; \
      float sc1 = it ? ksl.y : ksl.x, m1 = it ? kml.y : kml.x; \
      float sc2 = it ? ksh.y : ksh.x, m2 = it ? kmh.y : kmh.x; \
      float2 cs = ct0[it]; \
      _Pragma("unroll") \
      for (int ii = 0; ii < 8; ii++) { \
        float v1 = (float)((w1 >> (4 * ii)) & 15u) * sc1 + m1; \
        float v2 = (float)((w2 >> (4 * ii)) & 15u) * sc2 + m2; \
        int t = w * 8 + ii; \
        Kt[(t * 128 + lane)      ^ ((t & 7) << 3)] = f2bf(v1 * cs.x - v2 * cs.y); \
        Kt[(t * 128 + lane + 64) ^ ((t & 7) << 3)] = f2bf(v2 * cs.x + v1 * cs.y); \
        float nx = cs.x * csd.x - cs.y * csd.y; \
        cs.y = cs.y * csd.x + cs.x * csd.y; \
        cs.x = nx; \
      } \
    } } while(0)
#define PVSTEP() do { \
    f32x4 pv[4] = {zf, zf, zf, zf}; f32x4 ls = zf; \
    _Pragma("unroll") \
    for (int ks = 0; ks < 2; ks++) { \
      bf16x8 af = *(const bf16x8*)&Pt[((mt*16 + lr)*64 + ks*32 + lq*8) ^ sx]; \
      ls = MFMA16(af, onev, ls); \
      _Pragma("unroll") \
      for (int nt = 0; nt < 4; nt++) { \
        bf16x8 bv = *(const bf16x8*)&Vt[((nh*64 + nt*16 + lr)*64 + ks*32 + lq*8) ^ sx]; \
        pv[nt] = MFMA16(af, bv, pv[nt]); \
      } \
    } \
    _Pragma("unroll") \
    for (int r = 0; r < 4; r++) { \
      l_run[r] = l_run[r] * alpha[r] + ls[r]; \
      _Pragma("unroll") \
      for (int nt = 0; nt < 4; nt++) \
        oacc[nt][r] = oacc[nt][r] * alpha[r] + pv[nt][r]; \
    } } while(0)

  // ---- prologue: K(c0) -> Kt; refill K regs with c0+1 (always quant) ----
  KLOAD(c0);
  VLOAD(c0);
  KDEQ(c0);
  KLOAD(c0 + 1);
  bar();

  for (int i = 0; i < N; i++) {
    int c = c0 + i;
    // ================= P1: S(c) + PV(c-1) =================
    f32x4 sa0 = zf, sa1 = zf;
    #pragma unroll
    for (int ks = 0; ks < 4; ks++) {
      bf16x8 b0 = *(const bf16x8*)&Kt[((nh*32 + lr)*128      + ks*32 + lq*8) ^ sx];
      bf16x8 b1 = *(const bf16x8*)&Kt[((nh*32 + 16 + lr)*128 + ks*32 + lq*8) ^ sx];
      sa0 = MFMA16(qa[ks], b0, sa0);
      sa1 = MFMA16(qa[ks], b1, sa1);
    }
    if (i > 0) PVSTEP();                           // uses alpha from P2(i-1)
    #pragma unroll
    for (int r = 0; r < 4; r++) {
      sa0[r] *= 0.08838834764831845f;
      sa1[r] *= 0.08838834764831845f;
      float m0 = fmaxf(sa0[r], sa1[r]);
      m0 = RORMAX(m0, 0x128);                      // row_ror:8
      m0 = RORMAX(m0, 0x124);                      // row_ror:4
      m0 = RORMAX(m0, 0x122);                      // row_ror:2
      m0 = RORMAX(m0, 0x121);                      // row_ror:1
      mx[r] = m0;
    }
    if (lr == 0) {
      #pragma unroll
      for (int r = 0; r < 4; r++) pmax[wv * 16 + lq * 4 + r] = mx[r];
    }
    sacc[0] = sa0; sacc[1] = sa1;
    bar();
    // ================= P2: softmax + stage tiles ==========
    #pragma unroll
    for (int r = 0; r < 4; r++) {
      float cm = fmaxf(mx[r], pmax[(wv ^ 2) * 16 + lq * 4 + r]);
      float mn2 = fmaxf(m_prev[r], cm);
      alpha[r] = __expf(m_prev[r] - mn2);          // 0 on first chunk
      m_prev[r] = mn2;
    }
    #pragma unroll
    for (int nt = 0; nt < 2; nt++) {
      #pragma unroll
      for (int r = 0; r < 4; r++) {
        float p = __expf(sacc[nt][r] - m_prev[r]);
        int q = mt * 16 + lq * 4 + r, k = nh * 32 + nt * 16 + lr;
        Pt[(q * 64 + k) ^ ((q & 7) << 3)] = f2bf(p);
      }
    }
    // V-stage(c)
    if (c != 62) {
      unsigned wds[4] = {vw.x, vw.y, vw.z, vw.w};
      #pragma unroll
      for (int it = 0; it < 4; it++) {
        unsigned wd = wds[it];
        #pragma unroll
        for (int ii = 0; ii < 8; ii++) {
          int d = (wv * 4 + it) * 8 + ii;
          Vt[(d * 64 + lane) ^ ((d & 7) << 3)] = f2bf((float)((wd >> (4 * ii)) & 15u) * vs + vm);
        }
      }
    } else {
      for (int u = tid; u < 1024; u += 256) {
        int dd = u >> 3, t8 = u & 7;
        *(uint4*)&Vt[(dd * 64 + t8 * 8) ^ ((dd & 7) << 3)] =
            *(const uint4*)&vfullT[(bh * 128 + dd) * 64 + t8 * 8];
      }
    }
    // K-stage(c+1)
    if (i + 1 < N) {
      if (c + 1 == 62) {
        for (int u = tid; u < 1024; u += 256) {
          int row = u >> 4, cc = u & 15;
          *(uint4*)&Kt[(row * 128 + cc * 8) ^ ((row & 7) << 3)] =
              *(const uint4*)&kfullb[(bh * 64 + row) * 128 + cc * 8];
        }
      } else {
        KDEQ(c + 1);
      }
    }
    // register prefetch for the NEXT P2 (flight spans P1(i+1))
    if (i + 2 < N && c + 2 < 62) KLOAD(c + 2);
    if (i + 1 < N && c + 1 < 62) VLOAD(c + 1);
    bar();
  }
  // ---- epilogue: PV of last chunk ----
  PVSTEP();

  u16* Ob = Opart + (size_t)((bh * 16 + grp) * 32) * 128;
  #pragma unroll
  for (int nt = 0; nt < 4; nt++)
    #pragma unroll
    for (int r = 0; r < 4; r++)
      Ob[(mt * 16 + lq * 4 + r) * 128 + nh * 64 + nt * 16 + lr] = f2bf(oacc[nt][r]);
  if (wv < 2 && lr == 0) {
    #pragma unroll
    for (int r = 0; r < 4; r++) {
      ml[((bh * 16 + grp) * 32 + mt * 16 + lq * 4 + r) * 2 + 0] = m_prev[r];
      ml[((bh * 16 + grp) * 32 + mt * 16 + lq * 4 + r) * 2 + 1] = l_run[r];
    }
  }
#undef KLOAD
#undef VLOAD
#undef KDEQ
#undef PVSTEP
}

// ---------------------------------------------------------------------------
// Combine 16 group partials per bh. Grid (64, 4 d-quarters).
// ---------------------------------------------------------------------------
__global__ __launch_bounds__(256) void combine_kernel(
    const u16* __restrict__ Opart, const float* __restrict__ ml, u16* __restrict__ attn_out)
{
  int bh = blockIdx.x, dq = blockIdx.y, tid = threadIdx.x;
  __shared__ float Wg[16][33];
  __shared__ float Ls[32];
  if (tid < 32) {
    int row = tid;
    float M = -INFINITY;
    for (int g = 0; g < 16; g++)
      M = fmaxf(M, ml[((bh * 16 + g) * 32 + row) * 2]);
    float Lacc = 0.f;
    for (int g = 0; g < 16; g++) {
      float m = ml[((bh * 16 + g) * 32 + row) * 2];
      float l = ml[((bh * 16 + g) * 32 + row) * 2 + 1];
      float w = __expf(m - M);
      Wg[g][row] = w;
      Lacc += l * w;
    }
    Ls[row] = Lacc;
  }
  __syncthreads();
  int row = tid >> 3, ds = tid & 7;
  int d0 = dq * 32 + ds * 4;
  float a0 = 0.f, a1 = 0.f, a2 = 0.f, a3 = 0.f;
  for (int g = 0; g < 16; g++) {
    float w = Wg[g][row];
    const u16* p = Opart + (size_t)((bh * 16 + g) * 32 + row) * 128 + d0;
    uint2 v = *(const uint2*)p;
    const u16* h = (const u16*)&v;
    a0 += w * b2f(h[0]); a1 += w * b2f(h[1]); a2 += w * b2f(h[2]); a3 += w * b2f(h[3]);
  }
  float inv = 1.0f / Ls[row];
  int b = bh >> 3, kvh = bh & 7, hg = row >> 3, qp = row & 7;
  u16* dst = attn_out + (size_t)(b * 8 + qp) * 4096 + (kvh * 4 + hg) * 128 + d0;
  dst[0] = f2bf(a0 * inv); dst[1] = f2bf(a1 * inv);
  dst[2] = f2bf(a2 * inv); dst[3] = f2bf(a3 * inv);
}

// ---------------------------------------------------------------------------
// Sum 8 Wo K-split partials, emit final output in detected dtype.
// ---------------------------------------------------------------------------
__global__ __launch_bounds__(256) void cast_kernel(
    const float* __restrict__ O32, const int* __restrict__ flagp, void* __restrict__ out)
{
  int i = blockIdx.x * 256 + threadIdx.x;          // 262144 exact
  float v = c8(O32, i, 262144);
  if (*flagp) ((u16*)out)[i] = f2bf(v);
  else        ((float*)out)[i] = v;
}

// ---------------------------------------------------------------------------
extern "C" void kernel_launch(void* const* d_in, const int* in_sizes, int n_in,
                              void* d_out, int out_size, void* d_ws, size_t ws_size,
                              hipStream_t stream)
{
  const void* hidden = d_in[0];
  const void* Wq  = d_in[1];
  const void* Wk  = d_in[2];
  const void* Wv  = d_in[3];
  const void* Wo  = d_in[4];
  const int*  kqw = (const int*)d_in[5];
  const void* ksc = d_in[6];
  const void* kmn = d_in[7];
  const void* kfp = d_in[8];
  const int*  vqw = (const int*)d_in[9];
  const void* vsc = d_in[10];
  const void* vmn = d_in[11];
  const void* vfp = d_in[12];

  char* ws = (char*)d_ws;
  int*    flag     = (int*)(ws);                    //        256
  float2* ctab     = (float2*)(ws + 256);           //  2,064,384
  float*  Cq32     = (float*)(ws + 2064640);        // regionA 16,777,216:
  u16*    Opart    = (u16*)(ws + 2064640);          //   Cq32 12.6MB / Opart 8.4MB / O32 8.4MB
  float*  O32      = (float*)(ws + 2064640);        //   (pairwise-disjoint lifetimes)
  u16*    qrb      = (u16*)(ws + 18841856);         //    524,288 (attn_out overlays)
  u16*    attn_out = qrb;
  u16*    kfullb   = (u16*)(ws + 19366144);         //  1,048,576
  u16*    vfullT   = (u16*)(ws + 20414720);         //  1,048,576
  float*  ml       = (float*)(ws + 21463296);       //    524,288 (uses 262,144)

  ctab_proj_kernel<<<1776, 256, 0, stream>>>((const u16*)hidden, flag, ctab,
                                             Wq, Wk, Wv, Cq32);
  prep_kernel<<<5120, 256, 0, stream>>>(Cq32, kfp, vfp, ctab, flag, qrb, kfullb, vfullT);
  attn_kernel<<<dim3(64, 16), 256, 0, stream>>>(kqw, ksc, kmn, vqw, vsc, vmn,
                                                qrb, kfullb, vfullT, ctab, flag, Opart, ml);
  combine_kernel<<<dim3(64, 4), 256, 0, stream>>>(Opart, ml, attn_out);
  proj_kernel<<<dim3(64, 8), 256, 0, stream>>>(attn_out, Wo, Wo, Wo, O32, 4096, 0, 4096, flag, 0);
  cast_kernel<<<1024, 256, 0, stream>>>(O32, flag, d_out);
}